// Round 1
// baseline (4403.575 us; speedup 1.0000x reference)
//
#include <hip/hip_runtime.h>

// OutputPPBlock: out[n][h] = sum_{e: i[e]==n} (rbf[e] . W[h]) * x[e][h]
// E=2,000,000 edges, HIDDEN=128, NUM_RADIAL=6, NUM_NODES=100,000.
// Memory-bound: ~1.13 GB mandatory HBM traffic -> ~180us floor at 6.3 TB/s.
// Round 0: atomic-scatter baseline. 32 lanes/edge, float4 per lane.

constexpr int HIDDEN = 128;
constexpr int NRAD   = 6;

__global__ __launch_bounds__(256) void msg_scatter_kernel(
    const float* __restrict__ x,
    const float* __restrict__ rbf,
    const float* __restrict__ W,     // [HIDDEN][NRAD] row-major
    const int*   __restrict__ idx,   // [E]
    float*       __restrict__ out,   // [num_nodes][HIDDEN], pre-zeroed
    int E)
{
    __shared__ float sW[HIDDEN * NRAD];   // 3 KB
    for (int t = threadIdx.x; t < HIDDEN * NRAD; t += blockDim.x) sW[t] = W[t];
    __syncthreads();

    const int lane = threadIdx.x & 31;    // 32 lanes per edge
    const int egrp = threadIdx.x >> 5;    // edge slot within block (0..7)
    const int epb  = blockDim.x >> 5;     // 8 edges per block
    const int h0   = lane << 2;           // 4 hidden channels per lane

    // Per-lane W rows (4 rows x 6) -> registers once; they don't change per edge.
    float w[4][NRAD];
#pragma unroll
    for (int j = 0; j < 4; ++j)
#pragma unroll
        for (int r = 0; r < NRAD; ++r)
            w[j][r] = sW[(h0 + j) * NRAD + r];

    for (int e = blockIdx.x * epb + egrp; e < E; e += gridDim.x * epb) {
        const float* rb = rbf + (size_t)e * NRAD;
        const float r0 = rb[0], r1 = rb[1], r2 = rb[2],
                    r3 = rb[3], r4 = rb[4], r5 = rb[5];

        float c[4];
#pragma unroll
        for (int j = 0; j < 4; ++j) {
            c[j] = w[j][0] * r0 + w[j][1] * r1 + w[j][2] * r2
                 + w[j][3] * r3 + w[j][4] * r4 + w[j][5] * r5;
        }

        const float4 xv = *reinterpret_cast<const float4*>(
            x + (size_t)e * HIDDEN + h0);

        const int node = idx[e];
        float* o = out + (size_t)node * HIDDEN + h0;
        atomicAdd(o + 0, c[0] * xv.x);
        atomicAdd(o + 1, c[1] * xv.y);
        atomicAdd(o + 2, c[2] * xv.z);
        atomicAdd(o + 3, c[3] * xv.w);
    }
}

extern "C" void kernel_launch(void* const* d_in, const int* in_sizes, int n_in,
                              void* d_out, int out_size, void* d_ws, size_t ws_size,
                              hipStream_t stream) {
    const float* x   = (const float*)d_in[0];   // [E,128]
    const float* rbf = (const float*)d_in[1];   // [E,6]
    const float* W   = (const float*)d_in[2];   // [128,6]
    const int*   idx = (const int*)d_in[3];     // [E]
    float* out = (float*)d_out;                 // [num_nodes,128]

    const int E = in_sizes[3];

    // Harness poisons d_out with 0xAA every call; we accumulate, so zero it.
    hipMemsetAsync(d_out, 0, (size_t)out_size * sizeof(float), stream);

    const int epb = 8;                          // edges per 256-thread block
    const int blocks = (E + epb - 1) / epb;
    msg_scatter_kernel<<<blocks, 256, 0, stream>>>(x, rbf, W, idx, out, E);
}